// Round 4
// baseline (74.567 us; speedup 1.0000x reference)
//
#include <hip/hip_runtime.h>
#include <hip/hip_bf16.h>
#include <math.h>

// BahdanauAttention on MI355X (gfx950).
// query (16,64,1024) f32, keys (16,128,1024) f32, Wq/Wk (1024,1024) f32,
// la (1024), scalar (1), bias (1024). Outputs: context (16,64,1024) then
// scores (16,64,128), concatenated flat f32.
//
// K0 cast:    query/keys/Wq/Wk -> bf16 (RNE) in ws
// K1 prep_la: la2 = 2*la/||la||*scal; Sla = sum(la/||la||*scal)
// K2 gemm:    aq = ALPHA*(q@Wq^T); ak = ALPHA*(k@Wk^T + bias)   [bf16 MFMA, f32 acc]
// K3 fused:   scores = Sla - sum_n la2[n]/(1+exp2(aq+ak)); softmax; ctx = p@keys

#define ALPHA_2LOG2E 2.8853900817779268f
#define LOG2E 1.4426950408889634f

typedef __attribute__((ext_vector_type(8))) short short8;
typedef __attribute__((ext_vector_type(4))) float f32x4;

static __device__ __forceinline__ short f2bf(float f) {
    union { float f; unsigned u; } v; v.f = f;
    unsigned r = v.u + 0x7fffu + ((v.u >> 16) & 1u);   // round-nearest-even
    return (short)(r >> 16);
}

// ---------------- K0: fp32 -> bf16 cast ----------------
// blocks: [0,512) query(1M), [512,1536) keys(2M), [1536,2048) Wq, [2048,2560) Wk
__global__ __launch_bounds__(256) void cast_kernel(
    const float* __restrict__ q, const float* __restrict__ k,
    const float* __restrict__ wq, const float* __restrict__ wk,
    short* __restrict__ qb, short* __restrict__ kb,
    short* __restrict__ wqb, short* __restrict__ wkb)
{
    const int bid = blockIdx.x;
    const float* src; short* dst; int base;
    if (bid < 512)       { src = q;  dst = qb;  base = bid; }
    else if (bid < 1536) { src = k;  dst = kb;  base = bid - 512; }
    else if (bid < 2048) { src = wq; dst = wqb; base = bid - 1536; }
    else                 { src = wk; dst = wkb; base = bid - 2048; }
    const size_t i = ((size_t)base * 256 + threadIdx.x) * 8;
    float4 a = *reinterpret_cast<const float4*>(src + i);
    float4 b = *reinterpret_cast<const float4*>(src + i + 4);
    short8 o;
    o[0] = f2bf(a.x); o[1] = f2bf(a.y); o[2] = f2bf(a.z); o[3] = f2bf(a.w);
    o[4] = f2bf(b.x); o[5] = f2bf(b.y); o[6] = f2bf(b.z); o[7] = f2bf(b.w);
    *reinterpret_cast<short8*>(dst + i) = o;
}

// ---------------- K1: prepare la2 and Sla ----------------
__global__ __launch_bounds__(256) void prep_la_kernel(
    const float* __restrict__ la, const float* __restrict__ scal,
    float* __restrict__ la2, float* __restrict__ sla)
{
    __shared__ float red[4];
    const int t = threadIdx.x, lane = t & 63, w = t >> 6;
    float ss = 0.f;
    for (int i = t; i < 1024; i += 256) { float v = la[i]; ss = fmaf(v, v, ss); }
    #pragma unroll
    for (int off = 32; off; off >>= 1) ss += __shfl_xor(ss, off, 64);
    if (lane == 0) red[w] = ss;
    __syncthreads();
    const float tot = red[0] + red[1] + red[2] + red[3];
    const float sc = scal[0] / sqrtf(tot);
    float s2 = 0.f;
    for (int i = t; i < 1024; i += 256) {
        float v = la[i] * sc;
        la2[i] = 2.f * v;
        s2 += v;
    }
    #pragma unroll
    for (int off = 32; off; off >>= 1) s2 += __shfl_xor(s2, off, 64);
    __syncthreads();
    if (lane == 0) red[w] = s2;
    __syncthreads();
    if (t == 0) sla[0] = red[0] + red[1] + red[2] + red[3];
}

// ---------------- K2: bf16 MFMA NT-GEMM ----------------
// C[M][1024] = ALPHA*(A[M][1024] @ W[1024][1024]^T [+ bias]), A/W bf16, C f32.
// Tile BM=128 x BN=64, BK=32. 256 thr = 4 waves in 2x2; wave tile 64x32
// (4 m-frags x 2 n-frags of 16x16; mfma_f32_16x16x32_bf16).
// Reg-staged double-buffered LDS; raw s_barrier + lgkmcnt-only drains so the
// 2-tile-deep global prefetch stays in flight (T14; __syncthreads would
// drain vmcnt(0) and serialize).
__global__ __launch_bounds__(256) void gemm_mfma_kernel(
    const short* __restrict__ qb, const short* __restrict__ kb,
    const short* __restrict__ wqb, const short* __restrict__ wkb,
    const float* __restrict__ bias,
    float* __restrict__ aq, float* __restrict__ ak)
{
    __shared__ short As[2][128][32];
    __shared__ short Bs[2][64][32];

    const int bx = blockIdx.x, by = blockIdx.y;
    const short* A; const short* W; float* C; int useBias; int bm;
    if (bx < 8) { A = qb; W = wqb; C = aq; useBias = 0; bm = bx * 128; }
    else        { A = kb; W = wkb; C = ak; useBias = 1; bm = (bx - 8) * 128; }
    const int bn = by * 64;

    const int t = threadIdx.x;
    const int lane = t & 63, wid = t >> 6;
    const int wr = wid >> 1, wc = wid & 1;      // wave 2x2 -> 64x32 out tile
    const int fr = lane & 15, fg = lane >> 4;   // frag row/col, k-group

    // staging: thread t covers A rows {t>>2, t>>2+64} slot t&3, B row t>>2
    const int sRow = t >> 2, sSlot = t & 3;
    const short8* pA = (const short8*)(A + (size_t)bm * 1024);  // row stride 128 short8
    const short8* pB = (const short8*)(W + (size_t)bn * 1024);

    const f32x4 zero = {0.f, 0.f, 0.f, 0.f};
    f32x4 acc[4][2];
    #pragma unroll
    for (int mi = 0; mi < 4; ++mi)
        #pragma unroll
        for (int ni = 0; ni < 2; ++ni) acc[mi][ni] = zero;

    // prologue: tile0 -> buf0, issue tile1 loads
    short8 rA0 = pA[(size_t)sRow * 128 + sSlot];
    short8 rA1 = pA[(size_t)(sRow + 64) * 128 + sSlot];
    short8 rB  = pB[(size_t)sRow * 128 + sSlot];
    *(short8*)&As[0][sRow][sSlot * 8]      = rA0;
    *(short8*)&As[0][sRow + 64][sSlot * 8] = rA1;
    *(short8*)&Bs[0][sRow][sSlot * 8]      = rB;
    rA0 = pA[(size_t)sRow * 128 + 4 + sSlot];
    rA1 = pA[(size_t)(sRow + 64) * 128 + 4 + sSlot];
    rB  = pB[(size_t)sRow * 128 + 4 + sSlot];
    asm volatile("s_waitcnt lgkmcnt(0)" ::: "memory");
    __builtin_amdgcn_s_barrier();
    asm volatile("" ::: "memory");

    #pragma unroll 1
    for (int kt = 0; kt < 32; ++kt) {
        const int cur = kt & 1;
        // frag reads for tile kt (plain C++ -> compiler tracks lgkm deps)
        short8 af[4], bfr[2];
        #pragma unroll
        for (int mi = 0; mi < 4; ++mi)
            af[mi] = *(const short8*)&As[cur][wr * 64 + mi * 16 + fr][fg * 8];
        #pragma unroll
        for (int ni = 0; ni < 2; ++ni)
            bfr[ni] = *(const short8*)&Bs[cur][wc * 32 + ni * 16 + fr][fg * 8];
        // write tile kt+1 into other buffer (regs loaded 1 iter ago)
        if (kt < 31) {
            *(short8*)&As[cur ^ 1][sRow][sSlot * 8]      = rA0;
            *(short8*)&As[cur ^ 1][sRow + 64][sSlot * 8] = rA1;
            *(short8*)&Bs[cur ^ 1][sRow][sSlot * 8]      = rB;
        }
        // issue tile kt+2 global loads (in flight across the barrier)
        if (kt < 30) {
            const int koff = (kt + 2) * 4 + sSlot;
            rA0 = pA[(size_t)sRow * 128 + koff];
            rA1 = pA[(size_t)(sRow + 64) * 128 + koff];
            rB  = pB[(size_t)sRow * 128 + koff];
        }
        #pragma unroll
        for (int mi = 0; mi < 4; ++mi)
            #pragma unroll
            for (int ni = 0; ni < 2; ++ni)
                acc[mi][ni] = __builtin_amdgcn_mfma_f32_16x16x32_bf16(
                    af[mi], bfr[ni], acc[mi][ni], 0, 0, 0);
        asm volatile("s_waitcnt lgkmcnt(0)" ::: "memory");  // my ds reads+writes done
        __builtin_amdgcn_s_barrier();
        asm volatile("" ::: "memory");
    }

    // epilogue: C/D layout col=lane&15, row=(lane>>4)*4+reg  [m89-verified]
    float* Cb = C + (size_t)bm * 1024;
    float b0 = 0.f, b1 = 0.f;
    if (useBias) {
        b0 = bias[bn + wc * 32 + fr];
        b1 = bias[bn + wc * 32 + 16 + fr];
    }
    #pragma unroll
    for (int mi = 0; mi < 4; ++mi) {
        const int row0 = wr * 64 + mi * 16 + fg * 4;
        #pragma unroll
        for (int ni = 0; ni < 2; ++ni) {
            const int col = bn + wc * 32 + ni * 16 + fr;
            const float bb = ni ? b1 : b0;
            #pragma unroll
            for (int r = 0; r < 4; ++r)
                Cb[(size_t)(row0 + r) * 1024 + col] = (acc[mi][ni][r] + bb) * ALPHA_2LOG2E;
        }
    }
}

// ---------------- K3: fused scores + softmax + context ----------------
__global__ __launch_bounds__(256) void fused_kernel(
    const float* __restrict__ aq, const float* __restrict__ ak,
    const float* __restrict__ la2, const float* __restrict__ sla,
    const float* __restrict__ keys,
    float* __restrict__ ctx, float* __restrict__ out_scores)
{
    const int b = blockIdx.x;
    const int q0 = blockIdx.y * 2;
    const int t = threadIdx.x;
    const int w = t >> 6;
    const int lane = t & 63;

    __shared__ float p_s[2][128];

    float la2r[16], aq0r[16], aq1r[16];
    const float* aq0p = aq + ((size_t)(b * 64 + q0) << 10);
    const float* aq1p = aq0p + 1024;
    #pragma unroll
    for (int j = 0; j < 16; ++j) {
        int n = lane + (j << 6);
        la2r[j] = la2[n];
        aq0r[j] = aq0p[n];
        aq1r[j] = aq1p[n];
    }
    const float Sla = *sla;

    const float* akb = ak + ((size_t)(b * 128) << 10);
    for (int k = w * 32; k < w * 32 + 32; ++k) {
        const float* akrow = akb + ((size_t)k << 10);
        float acc0 = 0.f, acc1 = 0.f;
        #pragma unroll
        for (int j = 0; j < 16; ++j) {
            float akv = akrow[lane + (j << 6)];
            float r0 = __builtin_amdgcn_rcpf(1.f + __builtin_amdgcn_exp2f(aq0r[j] + akv));
            float r1 = __builtin_amdgcn_rcpf(1.f + __builtin_amdgcn_exp2f(aq1r[j] + akv));
            acc0 = fmaf(la2r[j], r0, acc0);
            acc1 = fmaf(la2r[j], r1, acc1);
        }
        #pragma unroll
        for (int off = 32; off; off >>= 1) {
            acc0 += __shfl_xor(acc0, off, 64);
            acc1 += __shfl_xor(acc1, off, 64);
        }
        if (lane == 0) {
            p_s[0][k] = Sla - acc0;
            p_s[1][k] = Sla - acc1;
        }
    }
    __syncthreads();

    if (w < 2) {
        float s0 = p_s[w][lane], s1 = p_s[w][lane + 64];
        float m = fmaxf(s0, s1);
        #pragma unroll
        for (int off = 32; off; off >>= 1) m = fmaxf(m, __shfl_xor(m, off, 64));
        float e0 = __builtin_amdgcn_exp2f((s0 - m) * LOG2E);
        float e1 = __builtin_amdgcn_exp2f((s1 - m) * LOG2E);
        float s = e0 + e1;
        #pragma unroll
        for (int off = 32; off; off >>= 1) s += __shfl_xor(s, off, 64);
        float inv = __builtin_amdgcn_rcpf(s);
        float p0 = e0 * inv, p1 = e1 * inv;
        p_s[w][lane] = p0;
        p_s[w][lane + 64] = p1;
        float* os = out_scores + (size_t)(b * 64 + q0 + w) * 128;
        os[lane] = p0;
        os[lane + 64] = p1;
    }
    __syncthreads();

    {
        const int n0 = t * 4;
        const float* kb = keys + ((size_t)(b * 128) << 10);
        float4 c0 = {0.f, 0.f, 0.f, 0.f}, c1 = {0.f, 0.f, 0.f, 0.f};
        for (int k = 0; k < 128; ++k) {
            float4 kv = *reinterpret_cast<const float4*>(kb + ((size_t)k << 10) + n0);
            float p0 = p_s[0][k], p1 = p_s[1][k];
            c0.x = fmaf(p0, kv.x, c0.x); c0.y = fmaf(p0, kv.y, c0.y);
            c0.z = fmaf(p0, kv.z, c0.z); c0.w = fmaf(p0, kv.w, c0.w);
            c1.x = fmaf(p1, kv.x, c1.x); c1.y = fmaf(p1, kv.y, c1.y);
            c1.z = fmaf(p1, kv.z, c1.z); c1.w = fmaf(p1, kv.w, c1.w);
        }
        float* c0p = ctx + (size_t)(b * 64 + q0) * 1024 + n0;
        *reinterpret_cast<float4*>(c0p) = c0;
        *reinterpret_cast<float4*>(c0p + 1024) = c1;
    }
}

extern "C" void kernel_launch(void* const* d_in, const int* in_sizes, int n_in,
                              void* d_out, int out_size, void* d_ws, size_t ws_size,
                              hipStream_t stream) {
    const float* query  = (const float*)d_in[0];
    const float* keys   = (const float*)d_in[1];
    const float* Wq     = (const float*)d_in[2];
    const float* Wk     = (const float*)d_in[3];
    const float* la     = (const float*)d_in[4];
    const float* scal   = (const float*)d_in[5];
    const float* bias   = (const float*)d_in[6];

    float* ws  = (float*)d_ws;
    float* aq  = ws;                        // 1M f32 (4 MB)
    float* ak  = ws + (1u << 20);           // 2M f32 (8 MB)
    float* la2 = ak + (2u << 20);           // 1024 f32
    float* sla = la2 + 1024;                // 1 f32
    // bf16 buffers, 16B-aligned offset (3*2^20 + 2048 floats)
    short* qb  = (short*)(ws + 3 * 1048576 + 2048);  // 1M bf16 (2 MB)
    short* kb  = qb + 1048576;                       // 2M bf16 (4 MB)
    short* wqb = kb + 2097152;                       // 1M bf16 (2 MB)
    short* wkb = wqb + 1048576;                      // 1M bf16 (2 MB)
    // total ws use ~22.6 MB

    float* ctx        = (float*)d_out;
    float* out_scores = ctx + (size_t)16 * 64 * 1024;

    cast_kernel<<<2560, 256, 0, stream>>>(query, keys, Wq, Wk, qb, kb, wqb, wkb);
    prep_la_kernel<<<1, 256, 0, stream>>>(la, scal, la2, sla);
    gemm_mfma_kernel<<<dim3(24, 16), 256, 0, stream>>>(qb, kb, wqb, wkb, bias, aq, ak);
    fused_kernel<<<dim3(16, 32), 256, 0, stream>>>(aq, ak, la2, sla, keys, ctx, out_scores);
}